// Round 3
// baseline (1001.250 us; speedup 1.0000x reference)
//
#include <hip/hip_runtime.h>
#include <hip/hip_bf16.h>

// SRNN text encoder, restructured (all device inputs/outputs are FP32):
//   Phase 0: convert Wih_f/Wih_b/Whh_f/Whh_b/Wout -> bf16 in ws; gather+convert
//            the 256 used embedding rows (Xemb).
//   Phase 1: Gx[dir][b*32+t][2048] = Xemb @ Wih^T + (bih+bhh)   (fp32)
//   Phase 2: 32 sequential steps. Fwd chain (p) and bwd chain (e) share states
//            across all spans; running fp32 prefix-sum of h gives span means.
//            Chain index: fwd c = p*8+b, bwd c = (31-e)*8+b (active: c>>3 <= step)
//            Snapshot at step i (k = i - (c>>3) >= 1) writes packed projection
//            row Apack[b*496 + off(k) + p_span][dir*512 + unit]  (bf16).
//   Phase 3: out = Apack @ Wout^T + bout  -> [3968][7680] fp32

#define BT __hip_bfloat16

typedef short bf16x8 __attribute__((ext_vector_type(8)));
typedef float f32x4 __attribute__((ext_vector_type(4)));

__device__ __forceinline__ bf16x8 ld_frag(const BT* p) {
    return *reinterpret_cast<const bf16x8*>(p);
}
__device__ __forceinline__ f32x4 mfma16(bf16x8 a, bf16x8 b, f32x4 c) {
    return __builtin_amdgcn_mfma_f32_16x16x32_bf16(a, b, c, 0, 0, 0);
}
__device__ __forceinline__ float sigm(float x) { return 1.0f / (1.0f + __expf(-x)); }

union B4 { BT b[4]; unsigned long long u; };

// ---------------- Phase 0a: fp32 -> bf16 weight conversion ----------------
// grid (512, 1, 5), block 256, grid-stride over float4s.
// Destination element offsets in Wbf: z0..z3 at z*1M (Wih_f,Wih_b,Whh_f,Whh_b),
// z4 (Wout, 7.5M elements) at 4M.   // BUGFIX r2: was 7M -> 3072-row shift
__global__ __launch_bounds__(256) void conv_kernel(
    const float* __restrict__ s0, const float* __restrict__ s1,
    const float* __restrict__ s2, const float* __restrict__ s3,
    const float* __restrict__ s4, BT* __restrict__ dbase)
{
    const int z = blockIdx.z;
    const float* src = (z == 0) ? s0 : (z == 1) ? s1 : (z == 2) ? s2 : (z == 3) ? s3 : s4;
    const int nel = (z == 4) ? 7864320 : 1048576;       // Wout : Wih/Whh
    BT* dst = dbase + (long)z * 1048576;                // z=4 -> 4M exactly
    const int n4 = nel >> 2;
    for (int i = blockIdx.x * 256 + threadIdx.x; i < n4; i += gridDim.x * 256) {
        float4 v = reinterpret_cast<const float4*>(src)[i];
        B4 t;
        t.b[0] = __float2bfloat16(v.x); t.b[1] = __float2bfloat16(v.y);
        t.b[2] = __float2bfloat16(v.z); t.b[3] = __float2bfloat16(v.w);
        reinterpret_cast<unsigned long long*>(dst)[i] = t.u;
    }
}

// ---------------- Phase 0b: gather + convert embeddings ----------------
// 256 rows x 512 cols; grid 128, block 256; one float4 per thread.
__global__ __launch_bounds__(256) void gather_kernel(
    const int* __restrict__ x, const float* __restrict__ emb, BT* __restrict__ Xemb)
{
    const int i = blockIdx.x * 256 + threadIdx.x;      // [0, 32768)
    const int r = i >> 7;                               // 128 float4 per row
    const int cq = i & 127;
    const long row = x[r];
    float4 v = reinterpret_cast<const float4*>(emb + row * 512)[cq];
    B4 t;
    t.b[0] = __float2bfloat16(v.x); t.b[1] = __float2bfloat16(v.y);
    t.b[2] = __float2bfloat16(v.z); t.b[3] = __float2bfloat16(v.w);
    reinterpret_cast<unsigned long long*>(Xemb + (long)r * 512)[cq] = t.u;
}

// ---------------- Phase 1: x-gates ----------------
// grid (8, 16, 2), block 256. Block = 32 rows x 128 cols (wave = 32 cols).
__global__ __launch_bounds__(256) void gx_kernel(
    const BT* __restrict__ Xemb,
    const BT* __restrict__ WihF, const BT* __restrict__ WihB,
    const float* __restrict__ bih_f, const float* __restrict__ bhh_f,
    const float* __restrict__ bih_b, const float* __restrict__ bhh_b,
    float* __restrict__ Gx)
{
    const int dir = blockIdx.z;
    const BT* Wih = dir ? WihB : WihF;
    const float* bih = dir ? bih_b : bih_f;
    const float* bhh = dir ? bhh_b : bhh_f;
    float* G = Gx + (long)dir * 256 * 2048;

    const int tid = threadIdx.x;
    const int w = tid >> 6, lane = tid & 63;
    const int m = lane & 15, q = lane >> 4;
    const int r0 = blockIdx.x * 32;
    const int c0 = blockIdx.y * 128 + w * 32;

    const BT* a0p = Xemb + (long)(r0 + m) * 512 + q * 8;
    const BT* a1p = Xemb + (long)(r0 + 16 + m) * 512 + q * 8;
    const BT* b0p = Wih + (long)(c0 + m) * 512 + q * 8;
    const BT* b1p = Wih + (long)(c0 + 16 + m) * 512 + q * 8;

    f32x4 acc[2][2] = {};
    for (int k0 = 0; k0 < 512; k0 += 32) {
        bf16x8 a0 = ld_frag(a0p + k0);
        bf16x8 a1 = ld_frag(a1p + k0);
        bf16x8 b0 = ld_frag(b0p + k0);
        bf16x8 b1 = ld_frag(b1p + k0);
        acc[0][0] = mfma16(a0, b0, acc[0][0]);
        acc[0][1] = mfma16(a0, b1, acc[0][1]);
        acc[1][0] = mfma16(a1, b0, acc[1][0]);
        acc[1][1] = mfma16(a1, b1, acc[1][1]);
    }
    #pragma unroll
    for (int rt = 0; rt < 2; ++rt)
        #pragma unroll
        for (int ct = 0; ct < 2; ++ct)
            #pragma unroll
            for (int reg = 0; reg < 4; ++reg) {
                int r = r0 + rt * 16 + q * 4 + reg;
                int c = c0 + ct * 16 + m;
                G[(long)r * 2048 + c] = acc[rt][ct][reg] + bih[c] + bhh[c];
            }
}

// ---------------- Phase 2: one recurrence step ----------------
// grid (rb, 16, 2), block 256 = 4 waves; wave w computes gate w's 32x32 tile.
__global__ __launch_bounds__(256) void step_kernel(
    const BT* __restrict__ WhhF, const BT* __restrict__ WhhB,
    const float* __restrict__ Gx,
    const BT* __restrict__ Hin, BT* __restrict__ Hout,
    float* __restrict__ C, float* __restrict__ S,
    BT* __restrict__ Apack, int step)
{
    const int dir = blockIdx.z;
    const BT* W = dir ? WhhB : WhhF;
    const float* G = Gx + (long)dir * 256 * 2048;
    const BT* Hi = Hin + (long)dir * 256 * 512;
    BT* Ho = Hout + (long)dir * 256 * 512;
    float* Cd = C + (long)dir * 256 * 512;
    float* Sd = S + (long)dir * 256 * 512;

    const int tid = threadIdx.x;
    const int w = tid >> 6, lane = tid & 63;
    const int m = lane & 15, q = lane >> 4;
    const int r0 = blockIdx.x * 32;
    const int u0 = blockIdx.y * 32;

    __shared__ float gbuf[4][32][33];

    f32x4 acc[2][2] = {};
    const BT* a0p = Hi + (long)(r0 + m) * 512 + q * 8;
    const BT* a1p = Hi + (long)(r0 + 16 + m) * 512 + q * 8;
    const BT* b0p = W + (long)(w * 512 + u0 + m) * 512 + q * 8;
    const BT* b1p = W + (long)(w * 512 + u0 + 16 + m) * 512 + q * 8;
    for (int k0 = 0; k0 < 512; k0 += 32) {
        bf16x8 a0 = ld_frag(a0p + k0);
        bf16x8 a1 = ld_frag(a1p + k0);
        bf16x8 b0 = ld_frag(b0p + k0);
        bf16x8 b1 = ld_frag(b1p + k0);
        acc[0][0] = mfma16(a0, b0, acc[0][0]);
        acc[0][1] = mfma16(a0, b1, acc[0][1]);
        acc[1][0] = mfma16(a1, b0, acc[1][0]);
        acc[1][1] = mfma16(a1, b1, acc[1][1]);
    }
    #pragma unroll
    for (int rt = 0; rt < 2; ++rt)
        #pragma unroll
        for (int ct = 0; ct < 2; ++ct)
            #pragma unroll
            for (int reg = 0; reg < 4; ++reg)
                gbuf[w][rt * 16 + q * 4 + reg][ct * 16 + m] = acc[rt][ct][reg];
    __syncthreads();

    const int pos = dir ? (31 - step) : step;  // absolute position consumed
    for (int idx = tid; idx < 1024; idx += 256) {
        const int r = idx >> 5, ul = idx & 31;
        const int chain = r0 + r;
        const int d = chain >> 3;              // fwd: start p ; bwd: 31 - end e
        const int b = chain & 7;
        if (d > step) continue;                // chain not yet active
        const int u = u0 + ul;
        const float* gx = G + (long)(b * 32 + pos) * 2048 + u;
        const float gi = gbuf[0][r][ul] + gx[0];
        const float gf = gbuf[1][r][ul] + gx[512];
        const float gg = gbuf[2][r][ul] + gx[1024];
        const float go = gbuf[3][r][ul] + gx[1536];
        const long o = (long)chain * 512 + u;
        const float c_new = sigm(gf) * Cd[o] + sigm(gi) * tanhf(gg);
        const float h = sigm(go) * tanhf(c_new);
        Cd[o] = c_new;
        Ho[o] = __float2bfloat16(h);
        const float s_new = Sd[o] + h;
        Sd[o] = s_new;
        const int k = step - d;                // span length - 1
        if (k >= 1) {
            const int p_span = dir ? pos : d;
            const int off = (k - 1) * 32 - ((k - 1) * k) / 2;
            Apack[(long)(b * 496 + off + p_span) * 1024 + dir * 512 + u] =
                __float2bfloat16(s_new / (float)(k + 1));
        }
    }
}

// ---------------- Phase 3: projection ----------------
// grid (62, 120), block 256 = 4 waves 2x2; block tile 64x64.
__global__ __launch_bounds__(256) void proj_kernel(
    const BT* __restrict__ Apack, const BT* __restrict__ Woutbf,
    const float* __restrict__ bout, float* __restrict__ out)
{
    const int tid = threadIdx.x;
    const int w = tid >> 6, lane = tid & 63;
    const int wr = w >> 1, wc = w & 1;
    const int m = lane & 15, q = lane >> 4;
    const int r0 = blockIdx.x * 64 + wr * 32;
    const int c0 = blockIdx.y * 64 + wc * 32;

    const BT* a0p = Apack + (long)(r0 + m) * 1024 + q * 8;
    const BT* a1p = Apack + (long)(r0 + 16 + m) * 1024 + q * 8;
    const BT* b0p = Woutbf + (long)(c0 + m) * 1024 + q * 8;
    const BT* b1p = Woutbf + (long)(c0 + 16 + m) * 1024 + q * 8;

    f32x4 acc[2][2] = {};
    for (int k0 = 0; k0 < 1024; k0 += 32) {
        bf16x8 a0 = ld_frag(a0p + k0);
        bf16x8 a1 = ld_frag(a1p + k0);
        bf16x8 b0 = ld_frag(b0p + k0);
        bf16x8 b1 = ld_frag(b1p + k0);
        acc[0][0] = mfma16(a0, b0, acc[0][0]);
        acc[0][1] = mfma16(a0, b1, acc[0][1]);
        acc[1][0] = mfma16(a1, b0, acc[1][0]);
        acc[1][1] = mfma16(a1, b1, acc[1][1]);
    }
    #pragma unroll
    for (int rt = 0; rt < 2; ++rt)
        #pragma unroll
        for (int ct = 0; ct < 2; ++ct)
            #pragma unroll
            for (int reg = 0; reg < 4; ++reg) {
                int r = r0 + rt * 16 + q * 4 + reg;
                int c = c0 + ct * 16 + m;
                out[(long)r * 7680 + c] = acc[rt][ct][reg] + bout[c];
            }
}

extern "C" void kernel_launch(void* const* d_in, const int* in_sizes, int n_in,
                              void* d_out, int out_size, void* d_ws, size_t ws_size,
                              hipStream_t stream) {
    const int*   x     = (const int*)d_in[0];
    const float* emb   = (const float*)d_in[2];
    const float* Wih_f = (const float*)d_in[3];
    const float* Whh_f = (const float*)d_in[4];
    const float* bih_f = (const float*)d_in[5];
    const float* bhh_f = (const float*)d_in[6];
    const float* Wih_b = (const float*)d_in[7];
    const float* Whh_b = (const float*)d_in[8];
    const float* bih_b = (const float*)d_in[9];
    const float* bhh_b = (const float*)d_in[10];
    const float* Wout  = (const float*)d_in[11];
    const float* bout  = (const float*)d_in[12];
    float* out = (float*)d_out;

    char* ws = (char*)d_ws;
    const long MB = 1 << 20;
    float* Gx    = (float*)(ws + 0);              // 4 MiB
    BT*    H0    = (BT*)(ws + 4 * MB);            // 512 KiB
    BT*    H1    = (BT*)(ws + 4 * MB + 512 * 1024);
    float* C     = (float*)(ws + 5 * MB);         // 1 MiB
    float* S     = (float*)(ws + 6 * MB);         // 1 MiB
    BT*    Apack = (BT*)(ws + 7 * MB);            // 7.75 MiB
    BT*    Xemb  = (BT*)(ws + 7 * MB + 7936 * 1024);  // 256 KiB (14.75..15 MiB)
    BT*    Wbf   = (BT*)(ws + 15 * MB);           // 23 MiB total -> ends at 38 MiB
    BT*    WihF  = Wbf;
    BT*    WihB  = Wbf + 1048576;
    BT*    WhhF  = Wbf + 2 * 1048576;
    BT*    WhhB  = Wbf + 3 * 1048576;
    BT*    Woutb = Wbf + 4 * 1048576;             // matches conv_kernel z=4

    // zero H0,H1,C,S (contiguous 3 MiB)
    hipMemsetAsync(ws + 4 * MB, 0, 3 * MB, stream);

    conv_kernel<<<dim3(512, 1, 5), 256, 0, stream>>>(
        Wih_f, Wih_b, Whh_f, Whh_b, Wout, Wbf);
    gather_kernel<<<128, 256, 0, stream>>>(x, emb, Xemb);

    gx_kernel<<<dim3(8, 16, 2), 256, 0, stream>>>(
        Xemb, WihF, WihB, bih_f, bhh_f, bih_b, bhh_b, Gx);

    for (int s = 0; s < 32; ++s) {
        const int rb = (8 * (s + 1) + 31) / 32;
        BT* Hin  = (s & 1) ? H1 : H0;
        BT* Hout = (s & 1) ? H0 : H1;
        step_kernel<<<dim3(rb, 16, 2), 256, 0, stream>>>(
            WhhF, WhhB, Gx, Hin, Hout, C, S, Apack, s);
    }

    proj_kernel<<<dim3(62, 120), 256, 0, stream>>>(Apack, Woutb, bout, out);
}

// Round 4
// 656.692 us; speedup vs baseline: 1.5247x; 1.5247x over previous
//
#include <hip/hip_runtime.h>
#include <hip/hip_bf16.h>

// SRNN text encoder, restructured (all device inputs/outputs are FP32):
//   Phase 0: convert Wih_f/Wih_b/Whh_f/Whh_b/Wout -> bf16 in ws; gather+convert
//            the 256 used embedding rows (Xemb).
//   Phase 1: Gx[dir][b*32+t][2048] = Xemb @ Wih^T + (bih+bhh)   (fp32)
//   Phase 2: 32 sequential steps. Fwd chain (p) and bwd chain (e) share states
//            across all spans; running fp32 prefix-sum of h gives span means.
//   Phase 3: out = Apack @ Wout^T + bout -> [3968][7680] fp32
//            R3: rewritten as 128x128 LDS-tiled MFMA GEMM w/ global_load_lds
//            + XOR-swizzled LDS chunks (bank-uniform ds_read_b128).

#define BT __hip_bfloat16

typedef short bf16x8 __attribute__((ext_vector_type(8)));
typedef float f32x4 __attribute__((ext_vector_type(4)));

__device__ __forceinline__ bf16x8 ld_frag(const BT* p) {
    return *reinterpret_cast<const bf16x8*>(p);
}
__device__ __forceinline__ f32x4 mfma16(bf16x8 a, bf16x8 b, f32x4 c) {
    return __builtin_amdgcn_mfma_f32_16x16x32_bf16(a, b, c, 0, 0, 0);
}
__device__ __forceinline__ float sigm(float x) { return 1.0f / (1.0f + __expf(-x)); }

// async 16B global -> LDS (wave-uniform LDS base + lane*16 hardware placement)
__device__ __forceinline__ void async16(const BT* g, BT* l) {
    __builtin_amdgcn_global_load_lds(
        (const __attribute__((address_space(1))) unsigned int*)g,
        (__attribute__((address_space(3))) unsigned int*)l,
        16, 0, 0);
}

union B4 { BT b[4]; unsigned long long u; };

// ---------------- Phase 0a: fp32 -> bf16 weight conversion ----------------
__global__ __launch_bounds__(256) void conv_kernel(
    const float* __restrict__ s0, const float* __restrict__ s1,
    const float* __restrict__ s2, const float* __restrict__ s3,
    const float* __restrict__ s4, BT* __restrict__ dbase)
{
    const int z = blockIdx.z;
    const float* src = (z == 0) ? s0 : (z == 1) ? s1 : (z == 2) ? s2 : (z == 3) ? s3 : s4;
    const int nel = (z == 4) ? 7864320 : 1048576;
    BT* dst = dbase + (long)z * 1048576;
    const int n4 = nel >> 2;
    for (int i = blockIdx.x * 256 + threadIdx.x; i < n4; i += gridDim.x * 256) {
        float4 v = reinterpret_cast<const float4*>(src)[i];
        B4 t;
        t.b[0] = __float2bfloat16(v.x); t.b[1] = __float2bfloat16(v.y);
        t.b[2] = __float2bfloat16(v.z); t.b[3] = __float2bfloat16(v.w);
        reinterpret_cast<unsigned long long*>(dst)[i] = t.u;
    }
}

// ---------------- Phase 0b: gather + convert embeddings ----------------
__global__ __launch_bounds__(256) void gather_kernel(
    const int* __restrict__ x, const float* __restrict__ emb, BT* __restrict__ Xemb)
{
    const int i = blockIdx.x * 256 + threadIdx.x;
    const int r = i >> 7;
    const int cq = i & 127;
    const long row = x[r];
    float4 v = reinterpret_cast<const float4*>(emb + row * 512)[cq];
    B4 t;
    t.b[0] = __float2bfloat16(v.x); t.b[1] = __float2bfloat16(v.y);
    t.b[2] = __float2bfloat16(v.z); t.b[3] = __float2bfloat16(v.w);
    reinterpret_cast<unsigned long long*>(Xemb + (long)r * 512)[cq] = t.u;
}

// ---------------- Phase 1: x-gates ----------------
__global__ __launch_bounds__(256) void gx_kernel(
    const BT* __restrict__ Xemb,
    const BT* __restrict__ WihF, const BT* __restrict__ WihB,
    const float* __restrict__ bih_f, const float* __restrict__ bhh_f,
    const float* __restrict__ bih_b, const float* __restrict__ bhh_b,
    float* __restrict__ Gx)
{
    const int dir = blockIdx.z;
    const BT* Wih = dir ? WihB : WihF;
    const float* bih = dir ? bih_b : bih_f;
    const float* bhh = dir ? bhh_b : bhh_f;
    float* G = Gx + (long)dir * 256 * 2048;

    const int tid = threadIdx.x;
    const int w = tid >> 6, lane = tid & 63;
    const int m = lane & 15, q = lane >> 4;
    const int r0 = blockIdx.x * 32;
    const int c0 = blockIdx.y * 128 + w * 32;

    const BT* a0p = Xemb + (long)(r0 + m) * 512 + q * 8;
    const BT* a1p = Xemb + (long)(r0 + 16 + m) * 512 + q * 8;
    const BT* b0p = Wih + (long)(c0 + m) * 512 + q * 8;
    const BT* b1p = Wih + (long)(c0 + 16 + m) * 512 + q * 8;

    f32x4 acc[2][2] = {};
    for (int k0 = 0; k0 < 512; k0 += 32) {
        bf16x8 a0 = ld_frag(a0p + k0);
        bf16x8 a1 = ld_frag(a1p + k0);
        bf16x8 b0 = ld_frag(b0p + k0);
        bf16x8 b1 = ld_frag(b1p + k0);
        acc[0][0] = mfma16(a0, b0, acc[0][0]);
        acc[0][1] = mfma16(a0, b1, acc[0][1]);
        acc[1][0] = mfma16(a1, b0, acc[1][0]);
        acc[1][1] = mfma16(a1, b1, acc[1][1]);
    }
    #pragma unroll
    for (int rt = 0; rt < 2; ++rt)
        #pragma unroll
        for (int ct = 0; ct < 2; ++ct)
            #pragma unroll
            for (int reg = 0; reg < 4; ++reg) {
                int r = r0 + rt * 16 + q * 4 + reg;
                int c = c0 + ct * 16 + m;
                G[(long)r * 2048 + c] = acc[rt][ct][reg] + bih[c] + bhh[c];
            }
}

// ---------------- Phase 2: one recurrence step ----------------
__global__ __launch_bounds__(256) void step_kernel(
    const BT* __restrict__ WhhF, const BT* __restrict__ WhhB,
    const float* __restrict__ Gx,
    const BT* __restrict__ Hin, BT* __restrict__ Hout,
    float* __restrict__ C, float* __restrict__ S,
    BT* __restrict__ Apack, int step)
{
    const int dir = blockIdx.z;
    const BT* W = dir ? WhhB : WhhF;
    const float* G = Gx + (long)dir * 256 * 2048;
    const BT* Hi = Hin + (long)dir * 256 * 512;
    BT* Ho = Hout + (long)dir * 256 * 512;
    float* Cd = C + (long)dir * 256 * 512;
    float* Sd = S + (long)dir * 256 * 512;

    const int tid = threadIdx.x;
    const int w = tid >> 6, lane = tid & 63;
    const int m = lane & 15, q = lane >> 4;
    const int r0 = blockIdx.x * 32;
    const int u0 = blockIdx.y * 32;

    __shared__ float gbuf[4][32][33];

    f32x4 acc[2][2] = {};
    const BT* a0p = Hi + (long)(r0 + m) * 512 + q * 8;
    const BT* a1p = Hi + (long)(r0 + 16 + m) * 512 + q * 8;
    const BT* b0p = W + (long)(w * 512 + u0 + m) * 512 + q * 8;
    const BT* b1p = W + (long)(w * 512 + u0 + 16 + m) * 512 + q * 8;
    for (int k0 = 0; k0 < 512; k0 += 32) {
        bf16x8 a0 = ld_frag(a0p + k0);
        bf16x8 a1 = ld_frag(a1p + k0);
        bf16x8 b0 = ld_frag(b0p + k0);
        bf16x8 b1 = ld_frag(b1p + k0);
        acc[0][0] = mfma16(a0, b0, acc[0][0]);
        acc[0][1] = mfma16(a0, b1, acc[0][1]);
        acc[1][0] = mfma16(a1, b0, acc[1][0]);
        acc[1][1] = mfma16(a1, b1, acc[1][1]);
    }
    #pragma unroll
    for (int rt = 0; rt < 2; ++rt)
        #pragma unroll
        for (int ct = 0; ct < 2; ++ct)
            #pragma unroll
            for (int reg = 0; reg < 4; ++reg)
                gbuf[w][rt * 16 + q * 4 + reg][ct * 16 + m] = acc[rt][ct][reg];
    __syncthreads();

    const int pos = dir ? (31 - step) : step;
    for (int idx = tid; idx < 1024; idx += 256) {
        const int r = idx >> 5, ul = idx & 31;
        const int chain = r0 + r;
        const int d = chain >> 3;
        const int b = chain & 7;
        if (d > step) continue;
        const int u = u0 + ul;
        const float* gx = G + (long)(b * 32 + pos) * 2048 + u;
        const float gi = gbuf[0][r][ul] + gx[0];
        const float gf = gbuf[1][r][ul] + gx[512];
        const float gg = gbuf[2][r][ul] + gx[1024];
        const float go = gbuf[3][r][ul] + gx[1536];
        const long o = (long)chain * 512 + u;
        const float c_new = sigm(gf) * Cd[o] + sigm(gi) * tanhf(gg);
        const float h = sigm(go) * tanhf(c_new);
        Cd[o] = c_new;
        Ho[o] = __float2bfloat16(h);
        const float s_new = Sd[o] + h;
        Sd[o] = s_new;
        const int k = step - d;
        if (k >= 1) {
            const int p_span = dir ? pos : d;
            const int off = (k - 1) * 32 - ((k - 1) * k) / 2;
            Apack[(long)(b * 496 + off + p_span) * 1024 + dir * 512 + u] =
                __float2bfloat16(s_new / (float)(k + 1));
        }
    }
}

// ---------------- Phase 3: projection (R3 rewrite) ----------------
// C[3968][7680] = Apack[3968][1024] @ Wout[7680][1024]^T + bout.
// grid (31, 60), block 256 = 4 waves (2x2 of 64x64); tile 128x128, BK=64.
// LDS tiles stored row-major [row][64] with XOR chunk swizzle:
//   LDS chunk slot s of row r holds global 8-elem chunk (s ^ (r&7)).
// Staging: lane i loads global chunk ((i&7)^(i>>3)) of row (L*8 + (i>>3)),
// which lands at LDS slot i*16B -> exactly the swizzled layout.
// Fragment reads then hit all 8 bank-quads uniformly (2 lanes/quad = free).
__global__ __launch_bounds__(256) void proj_kernel(
    const BT* __restrict__ Apack, const BT* __restrict__ Woutbf,
    const float* __restrict__ bout, float* __restrict__ out)
{
    __shared__ BT As[128 * 64];
    __shared__ BT Bs[128 * 64];

    const int tid = threadIdx.x;
    const int lane = tid & 63;
    const int wu = __builtin_amdgcn_readfirstlane(tid >> 6);
    const int m = lane & 15, q = lane >> 4;
    const int wr = wu >> 1, wc = wu & 1;
    const int r0 = blockIdx.x * 128;
    const int c0 = blockIdx.y * 128;

    const int srow = lane >> 3;             // 0..7 within 8-row staging group
    const int schunk = (lane & 7) ^ srow;   // swizzled global chunk index

    f32x4 acc[4][4] = {};

    for (int kc = 0; kc < 16; ++kc) {
        const int k0 = kc * 64;
        #pragma unroll
        for (int j = 0; j < 4; ++j) {
            const int L = wu * 4 + j;           // 0..15 staging group
            const int row = L * 8 + srow;       // 0..127 tile row
            async16(Apack + (long)(r0 + row) * 1024 + k0 + schunk * 8,
                    As + L * 512);
            async16(Woutbf + (long)(c0 + row) * 1024 + k0 + schunk * 8,
                    Bs + L * 512);
        }
        __syncthreads();
        #pragma unroll
        for (int ks = 0; ks < 2; ++ks) {
            const int slot = ((ks << 2) | q) ^ (m & 7);
            bf16x8 af[4], bf[4];
            #pragma unroll
            for (int t = 0; t < 4; ++t) {
                af[t] = ld_frag(As + (wr * 64 + t * 16 + m) * 64 + slot * 8);
                bf[t] = ld_frag(Bs + (wc * 64 + t * 16 + m) * 64 + slot * 8);
            }
            #pragma unroll
            for (int mt = 0; mt < 4; ++mt)
                #pragma unroll
                for (int nt = 0; nt < 4; ++nt)
                    acc[mt][nt] = mfma16(af[mt], bf[nt], acc[mt][nt]);
        }
        __syncthreads();
    }

    #pragma unroll
    for (int mt = 0; mt < 4; ++mt)
        #pragma unroll
        for (int nt = 0; nt < 4; ++nt)
            #pragma unroll
            for (int reg = 0; reg < 4; ++reg) {
                const int r = r0 + wr * 64 + mt * 16 + q * 4 + reg;
                const int c = c0 + wc * 64 + nt * 16 + m;
                out[(long)r * 7680 + c] = acc[mt][nt][reg] + bout[c];
            }
}

extern "C" void kernel_launch(void* const* d_in, const int* in_sizes, int n_in,
                              void* d_out, int out_size, void* d_ws, size_t ws_size,
                              hipStream_t stream) {
    const int*   x     = (const int*)d_in[0];
    const float* emb   = (const float*)d_in[2];
    const float* Wih_f = (const float*)d_in[3];
    const float* Whh_f = (const float*)d_in[4];
    const float* bih_f = (const float*)d_in[5];
    const float* bhh_f = (const float*)d_in[6];
    const float* Wih_b = (const float*)d_in[7];
    const float* Whh_b = (const float*)d_in[8];
    const float* bih_b = (const float*)d_in[9];
    const float* bhh_b = (const float*)d_in[10];
    const float* Wout  = (const float*)d_in[11];
    const float* bout  = (const float*)d_in[12];
    float* out = (float*)d_out;

    char* ws = (char*)d_ws;
    const long MB = 1 << 20;
    float* Gx    = (float*)(ws + 0);              // 4 MiB
    BT*    H0    = (BT*)(ws + 4 * MB);            // 512 KiB
    BT*    H1    = (BT*)(ws + 4 * MB + 512 * 1024);
    float* C     = (float*)(ws + 5 * MB);         // 1 MiB
    float* S     = (float*)(ws + 6 * MB);         // 1 MiB
    BT*    Apack = (BT*)(ws + 7 * MB);            // 7.75 MiB
    BT*    Xemb  = (BT*)(ws + 7 * MB + 7936 * 1024);  // 256 KiB
    BT*    Wbf   = (BT*)(ws + 15 * MB);           // 23 MiB -> ends at 38 MiB
    BT*    WihF  = Wbf;
    BT*    WihB  = Wbf + 1048576;
    BT*    WhhF  = Wbf + 2 * 1048576;
    BT*    WhhB  = Wbf + 3 * 1048576;
    BT*    Woutb = Wbf + 4 * 1048576;

    hipMemsetAsync(ws + 4 * MB, 0, 3 * MB, stream);

    conv_kernel<<<dim3(512, 1, 5), 256, 0, stream>>>(
        Wih_f, Wih_b, Whh_f, Whh_b, Wout, Wbf);
    gather_kernel<<<128, 256, 0, stream>>>(x, emb, Xemb);

    gx_kernel<<<dim3(8, 16, 2), 256, 0, stream>>>(
        Xemb, WihF, WihB, bih_f, bhh_f, bih_b, bhh_b, Gx);

    for (int s = 0; s < 32; ++s) {
        const int rb = (8 * (s + 1) + 31) / 32;
        BT* Hin  = (s & 1) ? H1 : H0;
        BT* Hout = (s & 1) ? H0 : H1;
        step_kernel<<<dim3(rb, 16, 2), 256, 0, stream>>>(
            WhhF, WhhB, Gx, Hin, Hout, C, S, Apack, s);
    }

    proj_kernel<<<dim3(31, 60), 256, 0, stream>>>(Apack, Woutb, bout, out);
}